// Round 5
// baseline (440.070 us; speedup 1.0000x reference)
//
#include <hip/hip_runtime.h>
#include <hip/hip_bf16.h>

typedef __bf16 bf16_t;
typedef __bf16 bfrag __attribute__((ext_vector_type(8)));
typedef float f4 __attribute__((ext_vector_type(4)));

#define S_LEN 2048
#define HQ_N 32
#define HK_N 8
#define D_DIM 64
#define LOG2E 1.4426950408889634f

// async global->LDS, 16B per lane; LDS dest = wave-uniform base + lane*16
#define GLDS16(gp, lp) __builtin_amdgcn_global_load_lds( \
    (const __attribute__((address_space(1))) void*)(gp), \
    (__attribute__((address_space(3))) void*)(lp), 16, 0, 0)

// ---------------------------------------------------------------------------
// fp32 -> bf16 elementwise convert (x). 8 elems/thread.
// ---------------------------------------------------------------------------
__global__ __launch_bounds__(256) void cvt_bf16(
    const float* __restrict__ src, bf16_t* __restrict__ dst, int n)
{
    int i = (blockIdx.x * 256 + threadIdx.x) * 8;
    if (i >= n) return;
    f4 a = *(const f4*)(src + i);
    f4 b = *(const f4*)(src + i + 4);
    bf16_t o[8];
#pragma unroll
    for (int j = 0; j < 4; ++j) { o[j] = (bf16_t)a[j]; o[4 + j] = (bf16_t)b[j]; }
    *(uint4*)(dst + i) = *(uint4*)o;
}

// ---------------------------------------------------------------------------
// Transpose + cvt: src fp32 [K][N] -> dst bf16 [N][K] (dst rows at row_off).
// ---------------------------------------------------------------------------
__global__ __launch_bounds__(256) void transpose_cvt(
    const float* __restrict__ src, bf16_t* __restrict__ dst,
    int K, int N, int row_off)
{
    __shared__ float T[32][33];
    const int n0 = blockIdx.x * 32;
    const int k0 = blockIdx.y * 32;
    const int tx = threadIdx.x;      // 0..31
    const int ty = threadIdx.y;      // 0..7
#pragma unroll
    for (int i = 0; i < 4; ++i)
        T[ty + 8 * i][tx] = src[(size_t)(k0 + ty + 8 * i) * N + n0 + tx];
    __syncthreads();
#pragma unroll
    for (int i = 0; i < 4; ++i)
        dst[(size_t)(row_off + n0 + ty + 8 * i) * K + k0 + tx] =
            (bf16_t)T[tx][ty + 8 * i];
}

// ---------------------------------------------------------------------------
// bf16 GEMM (m97-class): C[M,N] = A[M,K] * Bt[N,K]^T, glds staging.
// Tile 128x128, BK=64. LDS [128][64] unpadded; XOR chunk-swizzle
// (16B chunk c at row r holds global chunk c^(r&7)) -> contiguous lane-order
// for global_load_lds AND 2-way (free) banks on b128 fragment reads.
// ---------------------------------------------------------------------------
template<bool OUT_BF16>
__global__ __launch_bounds__(256) void gemm_bt(
    const bf16_t* __restrict__ A, const bf16_t* __restrict__ Bt,
    void* __restrict__ Cv, int M, int N, int K, int ldc)
{
    __shared__ bf16_t As[128][64];
    __shared__ bf16_t Bs[128][64];
    const int tid  = threadIdx.x;
    const int wave = tid >> 6;
    const int lane = tid & 63;
    const int lrow = lane & 15;
    const int quad = lane >> 4;
    const int wm   = (wave >> 1) * 64;
    const int wn   = (wave & 1) * 64;
    const int bm   = blockIdx.y * 128;
    const int bn   = blockIdx.x * 128;

    // staging: lane covers local row glr=lane>>3 (of 8), 16B chunk lane&7;
    // source chunk swizzled by row
    const int glr = lane >> 3;
    const int glc = (lane & 7) ^ glr;

    const bf16_t* Ab = A  + (size_t)(bm + glr) * K + glc * 8;
    const bf16_t* Bb = Bt + (size_t)(bn + glr) * K + glc * 8;

    f4 acc[4][4];
#pragma unroll
    for (int i = 0; i < 4; ++i)
#pragma unroll
        for (int j = 0; j < 4; ++j)
            acc[i][j] = (f4){0.f, 0.f, 0.f, 0.f};

    for (int k0 = 0; k0 < K; k0 += 64) {
        __syncthreads();   // prior iter's frag reads complete
#pragma unroll
        for (int t = 0; t < 4; ++t) {
            const int rb = wave * 8 + t * 32;   // wave-uniform 8-row band
            GLDS16(Ab + (size_t)rb * K + k0, &As[rb][0]);
            GLDS16(Bb + (size_t)rb * K + k0, &Bs[rb][0]);
        }
        __syncthreads();   // vmcnt(0) drain -> LDS populated

#pragma unroll
        for (int kc = 0; kc < 2; ++kc) {
            bfrag aF[4], bF[4];
#pragma unroll
            for (int i = 0; i < 4; ++i)
                aF[i] = *(const bfrag*)(&As[wm + i * 16 + lrow]
                                           [(((kc << 2) + quad) ^ (lrow & 7)) * 8]);
#pragma unroll
            for (int j = 0; j < 4; ++j)
                bF[j] = *(const bfrag*)(&Bs[wn + j * 16 + lrow]
                                           [(((kc << 2) + quad) ^ (lrow & 7)) * 8]);
#pragma unroll
            for (int i = 0; i < 4; ++i)
#pragma unroll
                for (int j = 0; j < 4; ++j)
                    acc[i][j] = __builtin_amdgcn_mfma_f32_16x16x32_bf16(
                        aF[i], bF[j], acc[i][j], 0, 0, 0);
        }
    }

    // C/D layout: col=lane&15, row=(lane>>4)*4+reg
#pragma unroll
    for (int i = 0; i < 4; ++i)
#pragma unroll
        for (int j = 0; j < 4; ++j)
#pragma unroll
            for (int r = 0; r < 4; ++r) {
                int row = bm + wm + i * 16 + quad * 4 + r;
                int col = bn + wn + j * 16 + lrow;
                if (OUT_BF16)
                    ((bf16_t*)Cv)[(size_t)row * ldc + col] = (bf16_t)acc[i][j][r];
                else
                    ((float*)Cv)[(size_t)row * ldc + col] = acc[i][j][r];
            }
}

// ---------------------------------------------------------------------------
// RoPE in-place on fused qkv bf16 [4096][3072]: q = cols h*64+d (h<32),
// k = cols 2048 + hk*64 + d. q additionally scaled by LOG2E.
// ---------------------------------------------------------------------------
__global__ __launch_bounds__(256) void rope_fused(
    bf16_t* __restrict__ t, const float* __restrict__ cs,
    const float* __restrict__ sn)
{
    int idx = blockIdx.x * 256 + threadIdx.x;   // row-major over [4096][1280]
    int cidx = idx % 1280;
    int row  = idx / 1280;
    int s    = row & (S_LEN - 1);
    int col, d1;
    float scale;
    if (cidx < 1024) {            // q
        d1 = cidx & 31;
        col = (cidx >> 5) * 64 + d1;
        scale = LOG2E;
    } else {                      // k
        int c2 = cidx - 1024;
        d1 = c2 & 31;
        col = 2048 + (c2 >> 5) * 64 + d1;
        scale = 1.0f;
    }
    size_t base = (size_t)row * 3072 + col;
    float t1 = (float)t[base];
    float t2 = (float)t[base + 32];
    float c  = cs[s * 32 + d1];
    float s_ = sn[s * 32 + d1];
    t[base]      = (bf16_t)((t1 * c - t2 * s_) * scale);
    t[base + 32] = (bf16_t)((t2 * c + t1 * s_) * scale);
}

// ---------------------------------------------------------------------------
// MFMA flash attention, TRANSPOSED formulation: S^T = K Q^T, O^T = V^T P^T.
// C-layout reg index r then runs along keys (S) / d (O), both contiguous ->
// mask loads are float4, P-writes and O-stores are b64. No-max softmax
// (scores << overflow bound; q pre-scaled by LOG2E -> p = exp2(s + m*LOG2E)).
// l via MFMA with ones A-fragment. Numerics identical to round-4 kernel.
// Block 256 = 4 waves; Q-tile 128 rows (wave owns 32); K-tiles of 64 keys.
// ---------------------------------------------------------------------------
__global__ __launch_bounds__(256) void attn_mfma(
    const bf16_t* __restrict__ qkv, const float* __restrict__ mask,
    bf16_t* __restrict__ o)
{
    __shared__ bf16_t Ks[64][72];    // [key][d]
    __shared__ bf16_t Vt[64][72];    // [d][key]
    __shared__ bf16_t Ps[128][72];   // [qrow][key], wave-private bands

    const int tid  = threadIdx.x;
    const int wave = tid >> 6;
    const int lane = tid & 63;
    const int lrow = lane & 15;
    const int quad = lane >> 4;
    const int qt   = blockIdx.x;     // 0..15
    const int h    = blockIdx.y;     // 0..31
    const int b    = blockIdx.z;     // 0..1
    const int hk   = h >> 2;
    const int s0   = qt * 128;
    const int wrow = wave * 32;

    // ones A-fragment: A[m][k] = (m==0)
    bfrag aOnes;
#pragma unroll
    for (int j = 0; j < 8; ++j) aOnes[j] = (lrow == 0) ? (bf16_t)1.0f : (bf16_t)0.0f;

    // Q as B-operand (B[k=d][n=qrow]): lane n=lrow -> qrow, k=quad*8+j -> d
    bfrag qf[2][2];
#pragma unroll
    for (int nt = 0; nt < 2; ++nt) {
        const bf16_t* qsrc = qkv + (size_t)(b * S_LEN + s0 + wrow + nt * 16 + lrow) * 3072 + h * 64;
#pragma unroll
        for (int kc = 0; kc < 2; ++kc)
            qf[nt][kc] = *(const bfrag*)(qsrc + kc * 32 + quad * 8);
    }

    f4 oacc[4][2], lacc[2];
#pragma unroll
    for (int nt = 0; nt < 2; ++nt) {
        lacc[nt] = (f4){0.f, 0.f, 0.f, 0.f};
#pragma unroll
        for (int dt = 0; dt < 4; ++dt) oacc[dt][nt] = (f4){0.f, 0.f, 0.f, 0.f};
    }

    const int skey = tid >> 2;        // K staging: key 0..63
    const int sdc  = (tid & 3) * 16;  // d chunk
    const int vg   = tid >> 5;        // V staging: key octet 0..7
    const int vp   = tid & 31;        // d pair 0..31

    for (int kt = 0; kt < 32; ++kt) {
        // ---- global prefetch of K/V tile ----
        const bf16_t* ksrc = qkv + (size_t)(b * S_LEN + kt * 64 + skey) * 3072 + 2048 + hk * 64 + sdc;
        uint4 k0v = *(const uint4*)(ksrc);
        uint4 k1v = *(const uint4*)(ksrc + 8);
        unsigned int vw[8];
#pragma unroll
        for (int kk = 0; kk < 8; ++kk)
            vw[kk] = *(const unsigned int*)(qkv + (size_t)(b * S_LEN + kt * 64 + vg * 8 + kk) * 3072
                                            + 2560 + hk * 64 + 2 * vp);
        __syncthreads();   // prior iteration's LDS reads complete
        *(uint4*)(&Ks[skey][sdc])     = k0v;
        *(uint4*)(&Ks[skey][sdc + 8]) = k1v;
        {   // V transpose: lane holds 8 keys x 2 dims -> 2 b128 row-writes
            unsigned short lo[8], hi[8];
#pragma unroll
            for (int kk = 0; kk < 8; ++kk) { lo[kk] = vw[kk] & 0xffff; hi[kk] = vw[kk] >> 16; }
            *(uint4*)(&Vt[2 * vp][vg * 8])     = *(uint4*)lo;
            *(uint4*)(&Vt[2 * vp + 1][vg * 8]) = *(uint4*)hi;
        }
        __syncthreads();

        // ---- mask: float4 loads (r runs along keys) ----
        f4 mk[2][4];
#pragma unroll
        for (int nt = 0; nt < 2; ++nt)
#pragma unroll
            for (int mt = 0; mt < 4; ++mt)
                mk[nt][mt] = *(const f4*)(mask
                    + (size_t)(s0 + wrow + nt * 16 + lrow) * S_LEN
                    + kt * 64 + mt * 16 + quad * 4);

        // ---- S^T = K Q^T: A = K[key][d] frags ----
        bfrag kf[4][2];
#pragma unroll
        for (int mt = 0; mt < 4; ++mt)
#pragma unroll
            for (int kc = 0; kc < 2; ++kc)
                kf[mt][kc] = *(const bfrag*)(&Ks[mt * 16 + lrow][kc * 32 + quad * 8]);

        f4 sc[4][2];
#pragma unroll
        for (int mt = 0; mt < 4; ++mt)
#pragma unroll
            for (int nt = 0; nt < 2; ++nt) {
                f4 a = (f4){0.f, 0.f, 0.f, 0.f};
                a = __builtin_amdgcn_mfma_f32_16x16x32_bf16(kf[mt][0], qf[nt][0], a, 0, 0, 0);
                a = __builtin_amdgcn_mfma_f32_16x16x32_bf16(kf[mt][1], qf[nt][1], a, 0, 0, 0);
                sc[mt][nt] = a;
            }

        // ---- p = exp2(s + mask*LOG2E); pack 4 keys -> one b64 LDS write ----
#pragma unroll
        for (int nt = 0; nt < 2; ++nt)
#pragma unroll
            for (int mt = 0; mt < 4; ++mt) {
                bf16_t pp[4];
#pragma unroll
                for (int r = 0; r < 4; ++r)
                    pp[r] = (bf16_t)exp2f(fmaf(mk[nt][mt][r], LOG2E, sc[mt][nt][r]));
                *(uint2*)(&Ps[wrow + nt * 16 + lrow][mt * 16 + quad * 4]) = *(uint2*)pp;
            }
        // wave-private rows: compiler lgkmcnt ordering suffices, no barrier

        // ---- O^T += V^T P^T ; l += 1 P^T ----
        bfrag pf[2][2], vf[4][2];
#pragma unroll
        for (int nt = 0; nt < 2; ++nt)
#pragma unroll
            for (int kc = 0; kc < 2; ++kc)
                pf[nt][kc] = *(const bfrag*)(&Ps[wrow + nt * 16 + lrow][kc * 32 + quad * 8]);
#pragma unroll
        for (int dt = 0; dt < 4; ++dt)
#pragma unroll
            for (int kc = 0; kc < 2; ++kc)
                vf[dt][kc] = *(const bfrag*)(&Vt[dt * 16 + lrow][kc * 32 + quad * 8]);
#pragma unroll
        for (int nt = 0; nt < 2; ++nt) {
#pragma unroll
            for (int dt = 0; dt < 4; ++dt) {
                oacc[dt][nt] = __builtin_amdgcn_mfma_f32_16x16x32_bf16(vf[dt][0], pf[nt][0], oacc[dt][nt], 0, 0, 0);
                oacc[dt][nt] = __builtin_amdgcn_mfma_f32_16x16x32_bf16(vf[dt][1], pf[nt][1], oacc[dt][nt], 0, 0, 0);
            }
            lacc[nt] = __builtin_amdgcn_mfma_f32_16x16x32_bf16(aOnes, pf[nt][0], lacc[nt], 0, 0, 0);
            lacc[nt] = __builtin_amdgcn_mfma_f32_16x16x32_bf16(aOnes, pf[nt][1], lacc[nt], 0, 0, 0);
        }
    }

    // ---- epilogue: l at C row 0 (lanes 0..15 hold cols); b64 O stores ----
#pragma unroll
    for (int nt = 0; nt < 2; ++nt) {
        float lv  = __shfl(lacc[nt][0], lrow, 64);   // src lane = (quad0, col=lrow)
        float inv = 1.f / lv;
        size_t rowb = (size_t)(b * S_LEN + s0 + wrow + nt * 16 + lrow) * 2048 + h * 64;
#pragma unroll
        for (int dt = 0; dt < 4; ++dt) {
            bf16_t ov[4];
#pragma unroll
            for (int r = 0; r < 4; ++r) ov[r] = (bf16_t)(oacc[dt][nt][r] * inv);
            *(uint2*)(o + rowb + dt * 16 + quad * 4) = *(uint2*)ov;
        }
    }
}

// ---------------------------------------------------------------------------
extern "C" void kernel_launch(void* const* d_in, const int* in_sizes, int n_in,
                              void* d_out, int out_size, void* d_ws, size_t ws_size,
                              hipStream_t stream)
{
    const float* x    = (const float*)d_in[0];
    const float* rc   = (const float*)d_in[1];
    const float* rs   = (const float*)d_in[2];
    const float* mask = (const float*)d_in[3];
    const float* Wq   = (const float*)d_in[4];
    const float* Wk   = (const float*)d_in[5];
    const float* Wv   = (const float*)d_in[6];
    const float* Wo   = (const float*)d_in[7];
    float* out = (float*)d_out;

    char* ws = (char*)d_ws;
    bf16_t* qkv = (bf16_t*)(ws);                  // [4096][3072] = 24 MiB
    bf16_t* xb  = (bf16_t*)(ws + (24u << 20));    // [4096][2048] = 16 MiB
    bf16_t* ob  = xb;                             // aliases xb (dead after QKV GEMM)
    bf16_t* Wt3 = (bf16_t*)(ws + (40u << 20));    // [3072][2048] = 12 MiB
    bf16_t* Wot = (bf16_t*)(ws + (52u << 20));    // [2048][2048] =  8 MiB

    const int M = 2 * S_LEN;  // 4096
    dim3 blk(256);

    // pre-pass: cvt x, transpose+cvt weights (Wq/Wk/Wv fused into Wt3)
    cvt_bf16<<<(M * 2048) / (256 * 8), blk, 0, stream>>>(x, xb, M * 2048);
    transpose_cvt<<<dim3(64, 64), dim3(32, 8), 0, stream>>>(Wq, Wt3, 2048, 2048, 0);
    transpose_cvt<<<dim3(16, 64), dim3(32, 8), 0, stream>>>(Wk, Wt3, 2048,  512, 2048);
    transpose_cvt<<<dim3(16, 64), dim3(32, 8), 0, stream>>>(Wv, Wt3, 2048,  512, 2560);
    transpose_cvt<<<dim3(64, 64), dim3(32, 8), 0, stream>>>(Wo, Wot, 2048, 2048, 0);

    // fused QKV projection: qkv[4096][3072] bf16
    gemm_bt<true><<<dim3(3072 / 128, M / 128), blk, 0, stream>>>(
        xb, Wt3, qkv, M, 3072, 2048, 3072);

    // RoPE on q (scaled by LOG2E) and k, in place
    rope_fused<<<(M * 1280) / 256, blk, 0, stream>>>(qkv, rc, rs);

    // attention -> ob[4096][2048] bf16
    attn_mfma<<<dim3(16, 32, 2), blk, 0, stream>>>(qkv, mask, ob);

    // out-projection -> fp32
    gemm_bt<false><<<dim3(2048 / 128, M / 128), blk, 0, stream>>>(
        ob, Wot, out, M, 2048, 2048, 2048);
}